// Round 3
// baseline (963.394 us; speedup 1.0000x reference)
//
#include <hip/hip_runtime.h>
#include <hip/hip_bf16.h>

#define SDIM 2048
#define DDIM 128
#define BHN  32
#define QB   64
#define KB   64

typedef __attribute__((ext_vector_type(8))) short bf16x8;
typedef __attribute__((ext_vector_type(4))) float f32x4;

#define MFMA16(a,b,c) __builtin_amdgcn_mfma_f32_16x16x32_bf16((a),(b),(c),0,0,0)

__device__ __forceinline__ short f2bf(float x) {
    union { float f; unsigned u; } a; a.f = x;
    unsigned r = a.u + 0x7fffu + ((a.u >> 16) & 1u);
    return (short)(r >> 16);
}

// stage a 64x128 f32 tile -> LDS bf16 [64][136] (row-padded, 16B aligned rows)
__device__ __forceinline__ void stage_qk(const float* __restrict__ g, short* __restrict__ lds,
                                         float scale, int tid) {
    #pragma unroll
    for (int it = 0; it < 4; ++it) {
        int c = tid + it * 256;           // 1024 chunks of 8 floats
        int row  = c >> 4;                // 16 chunks per row
        int col8 = (c & 15) << 3;
        const float4* gpv = (const float4*)(g + row * DDIM + col8);
        float4 x = gpv[0];
        float4 y = gpv[1];
        bf16x8 h;
        h[0] = f2bf(x.x * scale); h[1] = f2bf(x.y * scale);
        h[2] = f2bf(x.z * scale); h[3] = f2bf(x.w * scale);
        h[4] = f2bf(y.x * scale); h[5] = f2bf(y.y * scale);
        h[6] = f2bf(y.z * scale); h[7] = f2bf(y.w * scale);
        *(bf16x8*)&lds[row * 136 + col8] = h;
    }
}

// stage V 64x128 f32 -> transposed LDS bf16 Vt[d][k], rows padded to 72,
// k-column XOR-swizzled by bits of d to break staging write bank conflicts
__device__ __forceinline__ void stage_v(const float* __restrict__ g, short* __restrict__ lds, int tid) {
    #pragma unroll
    for (int it = 0; it < 4; ++it) {
        int c = tid + it * 256;
        int krow = c >> 4;
        int d0   = (c & 15) << 3;
        int kS   = krow ^ (((d0 >> 3) & 7) << 3);
        const float4* gpv = (const float4*)(g + krow * DDIM + d0);
        float4 x = gpv[0];
        float4 y = gpv[1];
        lds[(d0 + 0) * 72 + kS] = f2bf(x.x);
        lds[(d0 + 1) * 72 + kS] = f2bf(x.y);
        lds[(d0 + 2) * 72 + kS] = f2bf(x.z);
        lds[(d0 + 3) * 72 + kS] = f2bf(x.w);
        lds[(d0 + 4) * 72 + kS] = f2bf(y.x);
        lds[(d0 + 5) * 72 + kS] = f2bf(y.y);
        lds[(d0 + 6) * 72 + kS] = f2bf(y.z);
        lds[(d0 + 7) * 72 + kS] = f2bf(y.w);
    }
}

__global__ __launch_bounds__(256, 2)
void attn_fused(const float* __restrict__ q, const float* __restrict__ k,
                const float* __restrict__ v, float* __restrict__ out) {
    __shared__ short Qs[QB * 136];
    __shared__ short Ks[KB * 136];
    __shared__ short Vt[DDIM * 72];
    __shared__ short Pb[QB * 72];

    // heavy causal-wedge tiles (large qi) dispatched first -> shorter tail
    const int qi   = (SDIM / QB - 1) - blockIdx.x;
    const int bh   = blockIdx.y;
    const int q0   = qi * QB;
    const int tid  = threadIdx.x;
    const int w    = tid >> 6;      // wave id, owns q-rows 16w..16w+15
    const int lane = tid & 63;
    const int ln   = lane & 15;
    const int gp   = lane >> 4;

    const float* qg = q + ((size_t)bh * SDIM + q0) * DDIM;
    const float* kg = k + (size_t)bh * SDIM * DDIM;
    const float* vg = v + (size_t)bh * SDIM * DDIM;
    float* Og = out + ((size_t)bh * SDIM + q0) * DDIM;
    float* Wg = out + (size_t)BHN * SDIM * DDIM + ((size_t)bh * SDIM + q0) * SDIM;

    // scale folded into Q at staging time
    stage_qk(qg, Qs, 0.08838834764831845f, tid);
    __syncthreads();

    bf16x8 af[4];
    #pragma unroll
    for (int s = 0; s < 4; ++s)
        af[s] = *(const bf16x8*)&Qs[(16 * w + ln) * 136 + 32 * s + 8 * gp];

    const int nkt = qi + 1;

    // online softmax stats: lane-group gp holds rows 16w+4gp+r (r=0..3)
    float m_r[4], l_r[4];
    #pragma unroll
    for (int r = 0; r < 4; ++r) { m_r[r] = -3.0e38f; l_r[r] = 0.0f; }

    // ---------------- pass A: stats ----------------
    for (int kt = 0; kt < nkt; ++kt) {
        __syncthreads();
        stage_qk(kg + (size_t)kt * KB * DDIM, Ks, 1.0f, tid);
        __syncthreads();

        f32x4 acc[4];
        #pragma unroll
        for (int nt = 0; nt < 4; ++nt) acc[nt] = (f32x4){0.f, 0.f, 0.f, 0.f};
        #pragma unroll
        for (int nt = 0; nt < 4; ++nt) {
            #pragma unroll
            for (int s = 0; s < 4; ++s) {
                bf16x8 bk = *(const bf16x8*)&Ks[(16 * nt + ln) * 136 + 32 * s + 8 * gp];
                acc[nt] = MFMA16(af[s], bk, acc[nt]);
            }
        }

        const bool diag = (kt == qi);
        #pragma unroll
        for (int r = 0; r < 4; ++r) {
            const int qrow = q0 + 16 * w + 4 * gp + r;
            float vals[4];
            float tmax = -3.0e38f;
            #pragma unroll
            for (int nt = 0; nt < 4; ++nt) {
                float sv = acc[nt][r];
                int kcol = kt * KB + 16 * nt + ln;
                if (diag && kcol > qrow) sv = -3.0e38f;
                vals[nt] = sv;
                tmax = fmaxf(tmax, sv);
            }
            #pragma unroll
            for (int off = 1; off < 16; off <<= 1)
                tmax = fmaxf(tmax, __shfl_xor(tmax, off, 64));
            float mnew = fmaxf(m_r[r], tmax);
            float ssum = 0.f;
            #pragma unroll
            for (int nt = 0; nt < 4; ++nt) ssum += __expf(vals[nt] - mnew);
            #pragma unroll
            for (int off = 1; off < 16; off <<= 1)
                ssum += __shfl_xor(ssum, off, 64);
            l_r[r] = l_r[r] * __expf(m_r[r] - mnew) + ssum;
            m_r[r] = mnew;
        }
    }

    float il[4];
    #pragma unroll
    for (int r = 0; r < 4; ++r) il[r] = 1.0f / l_r[r];

    f32x4 accO[8];
    #pragma unroll
    for (int nt = 0; nt < 8; ++nt) accO[nt] = (f32x4){0.f, 0.f, 0.f, 0.f};

    // ---------------- pass B: P write + PV ----------------
    for (int kt = 0; kt < nkt; ++kt) {
        __syncthreads();
        stage_qk(kg + (size_t)kt * KB * DDIM, Ks, 1.0f, tid);
        stage_v(vg + (size_t)kt * KB * DDIM, Vt, tid);
        __syncthreads();

        f32x4 acc[4];
        #pragma unroll
        for (int nt = 0; nt < 4; ++nt) acc[nt] = (f32x4){0.f, 0.f, 0.f, 0.f};
        #pragma unroll
        for (int nt = 0; nt < 4; ++nt) {
            #pragma unroll
            for (int s = 0; s < 4; ++s) {
                bf16x8 bk = *(const bf16x8*)&Ks[(16 * nt + ln) * 136 + 32 * s + 8 * gp];
                acc[nt] = MFMA16(af[s], bk, acc[nt]);
            }
        }

        const bool diag = (kt == qi);
        #pragma unroll
        for (int nt = 0; nt < 4; ++nt) {
            #pragma unroll
            for (int r = 0; r < 4; ++r) {
                const int qrow_l = 16 * w + 4 * gp + r;
                const int kcol = kt * KB + 16 * nt + ln;
                float p = __expf(acc[nt][r] - m_r[r]) * il[r];
                if (diag && kcol > (q0 + qrow_l)) p = 0.f;
                Wg[(size_t)qrow_l * SDIM + kcol] = p;       // fp32 weights out
                Pb[qrow_l * 72 + 16 * nt + ln] = f2bf(p);   // bf16 for PV
            }
        }

        // PV: O += P * V   (A from Pb, B from swizzled Vt)
        #pragma unroll
        for (int s2 = 0; s2 < 2; ++s2) {
            bf16x8 ap = *(const bf16x8*)&Pb[(16 * w + ln) * 72 + 32 * s2 + 8 * gp];
            #pragma unroll
            for (int nt = 0; nt < 8; ++nt) {
                const int dcol = 16 * nt + ln;
                const int kS = (32 * s2 + 8 * gp) ^ (((dcol >> 3) & 7) << 3);
                bf16x8 bv = *(const bf16x8*)&Vt[dcol * 72 + kS];
                accO[nt] = MFMA16(ap, bv, accO[nt]);
            }
        }
    }

    // O epilogue
    #pragma unroll
    for (int nt = 0; nt < 8; ++nt) {
        #pragma unroll
        for (int r = 0; r < 4; ++r)
            Og[(size_t)(16 * w + 4 * gp + r) * DDIM + 16 * nt + ln] = accO[nt][r];
    }

    // zero-fill the masked (upper-triangle) weight columns
    const int zc0 = (qi + 1) * KB;
    if (zc0 < SDIM) {
        for (int row = 0; row < QB; ++row) {
            for (int c = zc0 + tid * 4; c < SDIM; c += 1024) {
                *(float4*)&Wg[(size_t)row * SDIM + c] = make_float4(0.f, 0.f, 0.f, 0.f);
            }
        }
    }
}

extern "C" void kernel_launch(void* const* d_in, const int* in_sizes, int n_in,
                              void* d_out, int out_size, void* d_ws, size_t ws_size,
                              hipStream_t stream) {
    const float* q = (const float*)d_in[0];
    const float* k = (const float*)d_in[1];
    const float* v = (const float*)d_in[2];
    float* out = (float*)d_out;
    dim3 grid(SDIM / QB, BHN);
    attn_fused<<<grid, dim3(256, 1, 1), 0, stream>>>(q, k, v, out);
}